// Round 3
// baseline (447.418 us; speedup 1.0000x reference)
//
#include <hip/hip_runtime.h>

typedef _Float16 half_t;
typedef _Float16 half8 __attribute__((ext_vector_type(8)));
typedef float float4v __attribute__((ext_vector_type(4)));

#define MFMA16(a, b, c) __builtin_amdgcn_mfma_f32_16x16x32_f16(a, b, c, 0, 0, 0)

// ---------------------------------------------------------------------------
// One kernel packs ALL weights: w0..w4 into MFMA B-fragment order (fp16,
// zero-padded) + w0 tail rows 576..579 to fp16 flat [4][256].
//   frag layout: out[((nt*nks+ks)*64+lane)*8+j] = W[ks*32+((lane>>4)<<3)+j][nt*16+(lane&15)]
// ---------------------------------------------------------------------------
__global__ void pack_all(const float* __restrict__ w0, const float* __restrict__ w1,
                         const float* __restrict__ w2, const float* __restrict__ w3,
                         const float* __restrict__ w4, half_t* __restrict__ w0p,
                         half_t* __restrict__ w1p, half_t* __restrict__ w2p,
                         half_t* __restrict__ w3p, half_t* __restrict__ w4p,
                         half_t* __restrict__ wtp) {
  const int bb = blockIdx.x;
  const float* w;
  half_t* out;
  int K, Nw, nks, base;
  if (bb < 576) {
    w = w0; out = w0p; K = 576; Nw = 256; nks = 18; base = 0;
  } else if (bb < 832) {
    w = w1; out = w1p; K = 256; Nw = 256; nks = 8; base = 576;
  } else if (bb < 1088) {
    w = w2; out = w2p; K = 256; Nw = 256; nks = 8; base = 832;
  } else if (bb < 1344) {
    w = w3; out = w3p; K = 256; Nw = 256; nks = 8; base = 1088;
  } else if (bb < 1360) {
    w = w4; out = w4p; K = 256; Nw = 3; nks = 8; base = 1344;
  } else {  // w0 tail rows 576..579 -> fp16
    const int id = threadIdx.x;
#pragma unroll
    for (int e = 0; e < 4; e++) wtp[e * 256 + id] = (half_t)w0[576 * 256 + e * 256 + id];
    return;
  }
  const int id = (bb - base) * 256 + threadIdx.x;
  const int j = id & 7;
  const int lane = (id >> 3) & 63;
  const int t3 = id >> 9;
  const int ks = t3 % nks;
  const int nt = t3 / nks;
  const int n = nt * 16 + (lane & 15);
  const int k = ks * 32 + ((lane >> 4) << 3) + j;
  float v = (k < K && n < Nw) ? w[k * Nw + n] : 0.0f;
  out[id] = (half_t)v;
}

// ---------------------------------------------------------------------------
// Z = conv3x3(feat, W0[0:576]) + b0, position-major fp16: Z[pos][256].
// ---------------------------------------------------------------------------
__global__ __launch_bounds__(256, 2) void conv_l0(
    const float* __restrict__ feat, const half_t* __restrict__ w0p,
    const float* __restrict__ b0, half_t* __restrict__ Z) {
  __shared__ alignas(16) half_t Xc[2][64][40];
  const int tid = threadIdx.x;
  const int lane = tid & 63, wave = tid >> 6, quad = lane >> 4, l15 = lane & 15;
  const int blk = blockIdx.x;
  const int b = blk >> 8;
  const int h = (blk >> 1) & 127;
  const int wbase = (blk & 1) << 6;
  const float* featB = feat + b * (64 * 128 * 128);

  auto stage = [&](int ks, int buf) {
#pragma unroll
    for (int e = 0; e < 8; e++) {
      const int idx = e * 256 + tid;
      const int row = idx >> 5;
      const int col = idx & 31;
      const int kk = ks * 32 + col;
      const int c = kk / 9;
      const int w9 = kk - c * 9;
      const int di = w9 / 3;
      const int dj = w9 - di * 3;
      const int y = h + di - 1;
      const int x = wbase + row + dj - 1;
      float v = 0.0f;
      if ((unsigned)y < 128u && (unsigned)x < 128u) v = featB[(c << 14) + (y << 7) + x];
      Xc[buf][row][col] = (half_t)v;
    }
  };

  const float4v zero4 = {0.0f, 0.0f, 0.0f, 0.0f};
  float4v acc[4][4];
#pragma unroll
  for (int mt = 0; mt < 4; mt++)
#pragma unroll
    for (int jn = 0; jn < 4; jn++) acc[mt][jn] = zero4;

  half8 bcur[4], bnxt[4];
#pragma unroll
  for (int jn = 0; jn < 4; jn++)
    bcur[jn] = *(const half8*)(w0p + ((((wave * 4 + jn) * 18 + 0) * 64 + lane) << 3));
  stage(0, 0);
  __syncthreads();

#pragma unroll 1
  for (int ks = 0; ks < 18; ks++) {
    const int buf = ks & 1;
    if (ks + 1 < 18) {
      stage(ks + 1, buf ^ 1);
#pragma unroll
      for (int jn = 0; jn < 4; jn++)
        bnxt[jn] =
            *(const half8*)(w0p + ((((wave * 4 + jn) * 18 + ks + 1) * 64 + lane) << 3));
    }
    half8 a[4];
#pragma unroll
    for (int mt = 0; mt < 4; mt++)
      a[mt] = *(const half8*)(&Xc[buf][mt * 16 + l15][quad * 8]);
#pragma unroll
    for (int mt = 0; mt < 4; mt++)
#pragma unroll
      for (int jn = 0; jn < 4; jn++) acc[mt][jn] = MFMA16(a[mt], bcur[jn], acc[mt][jn]);
#pragma unroll
    for (int jn = 0; jn < 4; jn++) bcur[jn] = bnxt[jn];
    __syncthreads();
  }

  const int posbase = b * 16384 + h * 128 + wbase;
#pragma unroll
  for (int jn = 0; jn < 4; jn++) {
    const int colg = wave * 64 + jn * 16 + l15;
    const float bb = b0[colg];
#pragma unroll
    for (int mt = 0; mt < 4; mt++)
#pragma unroll
      for (int rr = 0; rr < 4; rr++) {
        const int row = mt * 16 + quad * 4 + rr;
        Z[(size_t)(posbase + row) * 256 + colg] = (half_t)(acc[mt][jn][rr] + bb);
      }
  }
}

// ---------------------------------------------------------------------------
// Fused LIIF main, software-pipelined across corners:
//  - Z rows for corner t+1 prefetched into registers during corner t's GEMMs
//  - each layer's first B-fragments preloaded during previous layer's epilogue
//  - rank-4 rel/cell update in packed fp16 (v_pk_fma_f16)
// ---------------------------------------------------------------------------
__global__ __launch_bounds__(256, 4) void liif_main(
    const float* __restrict__ coord, const float* __restrict__ cell,
    const half_t* __restrict__ Zp, const half_t* __restrict__ wtp,
    const half_t* __restrict__ w1p, const half_t* __restrict__ w2p,
    const half_t* __restrict__ w3p, const half_t* __restrict__ w4p,
    const float* __restrict__ b1, const float* __restrict__ b2,
    const float* __restrict__ b3, const float* __restrict__ b4,
    float* __restrict__ outp) {
  __shared__ alignas(16) half_t Hs[64][264];
  __shared__ int pos4[4][64];
  __shared__ half_t relxh[4][64], relyh[4][64];
  __shared__ half_t cellxh[64], cellyh[64];
  __shared__ float area4[4][64];
  __shared__ float oacc[64][4];
  __shared__ float totv[64];

  const int tid = threadIdx.x;
  const int lane = tid & 63;
  const int wave = tid >> 6;
  const int quad = lane >> 4;
  const int l15 = lane & 15;
  const int blk = blockIdx.x;
  const int batch = blk >> 10;

  // ---- geometry: t = tid>>6 (corner), row = tid&63 (query) ----
  {
    const int t = tid >> 6, row = tid & 63;
    const int gq = blk * 64 + row;
    const float cx0 = coord[gq * 2 + 0], cy0 = coord[gq * 2 + 1];
    const float vx = (t & 2) ? 1.0f : -1.0f;
    const float vy = (t & 1) ? 1.0f : -1.0f;
    const float r = 1.0f / 128.0f, lim = 1.0f - 1e-6f, eps = 1e-6f;
    float cx = fminf(fmaxf(cx0 + vx * r + eps, -lim), lim);
    float cy = fminf(fmaxf(cy0 + vy * r + eps, -lim), lim);
    int ix = (int)floorf((cx + 1.0f) * 64.0f);
    ix = min(max(ix, 0), 127);
    int iy = (int)floorf((cy + 1.0f) * 64.0f);
    iy = min(max(iy, 0), 127);
    float qx = -1.0f + (2.0f * ix + 1.0f) * (1.0f / 128.0f);
    float qy = -1.0f + (2.0f * iy + 1.0f) * (1.0f / 128.0f);
    float rxv = (cx0 - qx) * 128.0f;
    float ryv = (cy0 - qy) * 128.0f;
    pos4[t][row] = (batch << 14) + (ix << 7) + iy;
    relxh[t][row] = (half_t)rxv;
    relyh[t][row] = (half_t)ryv;
    area4[t][row] = fabsf(rxv * ryv) + 1e-9f;
    if (t == 0) {
      cellxh[row] = (half_t)(cell[gq * 2 + 0] * 128.0f);
      cellyh[row] = (half_t)(cell[gq * 2 + 1] * 128.0f);
      oacc[row][0] = 0.0f;
      oacc[row][1] = 0.0f;
      oacc[row][2] = 0.0f;
      totv[row] = 0.0f;
    }
  }
  __syncthreads();

  const float4v zero4 = {0.0f, 0.0f, 0.0f, 0.0f};
  const int c8 = tid & 31;           // fixed 8-channel block
  const int rbase = (tid >> 5) * 8;  // rows rbase..rbase+7

  // per-thread rank-4 tail weights (fp16, fixed channels)
  const half8 wt0 = *(const half8*)(wtp + 0 * 256 + c8 * 8);
  const half8 wt1 = *(const half8*)(wtp + 1 * 256 + c8 * 8);
  const half8 wt2 = *(const half8*)(wtp + 2 * 256 + c8 * 8);
  const half8 wt3 = *(const half8*)(wtp + 3 * 256 + c8 * 8);
  const half8 zero8 = {0, 0, 0, 0, 0, 0, 0, 0};

  // prefetch corner 0's Z rows
  half8 zreg[8];
#pragma unroll
  for (int e = 0; e < 8; e++)
    zreg[e] = *(const half8*)(Zp + ((size_t)pos4[0][rbase + e] << 8) + c8 * 8);

  half8 bcur[4], bnxt[4], bf4[2];
  // preload L1 first B-fragments
#pragma unroll
  for (int jn = 0; jn < 4; jn++)
    bcur[jn] = *(const half8*)(w1p + ((((wave * 4 + jn) * 8 + 0) * 64 + lane) << 3));

#pragma unroll 1
  for (int t = 0; t < 4; t++) {
    // ---- rank-4 + ReLU -> Hs (packed fp16) ----
#pragma unroll
    for (int e = 0; e < 8; e++) {
      const int row = rbase + e;
      const half_t rx = relxh[t][row], ry = relyh[t][row];
      const half_t cx = cellxh[row], cy = cellyh[row];
      const half8 rx8 = {rx, rx, rx, rx, rx, rx, rx, rx};
      const half8 ry8 = {ry, ry, ry, ry, ry, ry, ry, ry};
      const half8 cx8 = {cx, cx, cx, cx, cx, cx, cx, cx};
      const half8 cy8 = {cy, cy, cy, cy, cy, cy, cy, cy};
      half8 v = zreg[e] + rx8 * wt0 + ry8 * wt1 + cx8 * wt2 + cy8 * wt3;
      v = __builtin_elementwise_max(v, zero8);
      *(half8*)(&Hs[row][c8 * 8]) = v;
    }
    __syncthreads();

    // prefetch next corner's Z rows (hidden behind L1..L3 MFMA)
    half8 znext[8];
    if (t < 3) {
#pragma unroll
      for (int e = 0; e < 8; e++)
        znext[e] = *(const half8*)(Zp + ((size_t)pos4[t + 1][rbase + e] << 8) + c8 * 8);
    }

    // ---- layers 1..3: K=256, in-place on Hs ----
    float4v acc[4][4];
#pragma unroll 1
    for (int L = 0; L < 3; L++) {
      const half_t* wp = (L == 0) ? w1p : (L == 1) ? w2p : w3p;
      const float* bp = (L == 0) ? b1 : (L == 1) ? b2 : b3;
#pragma unroll
      for (int mt = 0; mt < 4; mt++)
#pragma unroll
        for (int jn = 0; jn < 4; jn++) acc[mt][jn] = zero4;
#pragma unroll 1
      for (int ks = 0; ks < 8; ks++) {
        if (ks + 1 < 8) {
#pragma unroll
          for (int jn = 0; jn < 4; jn++)
            bnxt[jn] =
                *(const half8*)(wp + ((((wave * 4 + jn) * 8 + ks + 1) * 64 + lane) << 3));
        }
        half8 a[4];
#pragma unroll
        for (int mt = 0; mt < 4; mt++)
          a[mt] = *(const half8*)(&Hs[mt * 16 + l15][ks * 32 + quad * 8]);
#pragma unroll
        for (int mt = 0; mt < 4; mt++)
#pragma unroll
          for (int jn = 0; jn < 4; jn++)
            acc[mt][jn] = MFMA16(a[mt], bcur[jn], acc[mt][jn]);
#pragma unroll
        for (int jn = 0; jn < 4; jn++) bcur[jn] = bnxt[jn];
      }
      __syncthreads();  // all waves done READING Hs
      // preload next GEMM's first B-fragments (overlaps epilogue)
      if (L < 2) {
        const half_t* wpn = (L == 0) ? w2p : w3p;
#pragma unroll
        for (int jn = 0; jn < 4; jn++)
          bcur[jn] = *(const half8*)(wpn + ((((wave * 4 + jn) * 8 + 0) * 64 + lane) << 3));
      } else {
#pragma unroll
        for (int kx = 0; kx < 2; kx++)
          bf4[kx] = *(const half8*)(w4p + (((wave * 2 + kx) * 64 + lane) << 3));
      }
#pragma unroll
      for (int jn = 0; jn < 4; jn++) {
        const int colg = wave * 64 + jn * 16 + l15;
        const float bb = bp[colg];
#pragma unroll
        for (int mt = 0; mt < 4; mt++)
#pragma unroll
          for (int rr = 0; rr < 4; rr++) {
            float v = acc[mt][jn][rr] + bb;
            Hs[mt * 16 + quad * 4 + rr][colg] = (half_t)fmaxf(v, 0.0f);
          }
      }
      __syncthreads();
    }

    // ---- layer 4: 256 -> 3, K split across waves ----
    float4v acc4[4];
#pragma unroll
    for (int mt = 0; mt < 4; mt++) acc4[mt] = zero4;
#pragma unroll
    for (int kx = 0; kx < 2; kx++) {
      const int ks = wave * 2 + kx;
#pragma unroll
      for (int mt = 0; mt < 4; mt++) {
        half8 a = *(const half8*)(&Hs[mt * 16 + l15][ks * 32 + quad * 8]);
        acc4[mt] = MFMA16(a, bf4[kx], acc4[mt]);
      }
    }
    __syncthreads();  // Hs reads done -> reuse as S4 scratch
    // preload next corner's L1 first B-fragments (overlaps ensemble)
    if (t < 3) {
#pragma unroll
      for (int jn = 0; jn < 4; jn++)
        bcur[jn] = *(const half8*)(w1p + ((((wave * 4 + jn) * 8 + 0) * 64 + lane) << 3));
    }
    float* S4f = (float*)&Hs[0][0];
    if (l15 < 4) {
#pragma unroll
      for (int mt = 0; mt < 4; mt++)
#pragma unroll
        for (int rr = 0; rr < 4; rr++)
          S4f[(wave * 64 + mt * 16 + quad * 4 + rr) * 4 + l15] = acc4[mt][rr];
    }
    __syncthreads();

    if (tid < 192) {
      const int row = tid / 3;
      const int j = tid - row * 3;
      float pred = b4[j] + S4f[(0 * 64 + row) * 4 + j] + S4f[(1 * 64 + row) * 4 + j] +
                   S4f[(2 * 64 + row) * 4 + j] + S4f[(3 * 64 + row) * 4 + j];
      oacc[row][j] += pred * area4[3 - t][row];  // diagonal swap
    } else {
      const int row = tid - 192;
      totv[row] += area4[t][row];
    }
    __syncthreads();

#pragma unroll
    for (int e = 0; e < 8; e++) zreg[e] = znext[e];
  }

  if (tid < 192) {
    const int row = tid / 3;
    const int j = tid - row * 3;
    const int gq = blk * 64 + row;
    outp[gq * 3 + j] = oacc[row][j] / totv[row];
  }
}

// ---------------------------------------------------------------------------
extern "C" void kernel_launch(void* const* d_in, const int* in_sizes, int n_in,
                              void* d_out, int out_size, void* d_ws, size_t ws_size,
                              hipStream_t stream) {
  const float* feat = (const float*)d_in[0];
  const float* coord = (const float*)d_in[1];
  const float* cell = (const float*)d_in[2];
  const float* w0 = (const float*)d_in[3];
  const float* b0 = (const float*)d_in[4];
  const float* w1 = (const float*)d_in[5];
  const float* b1 = (const float*)d_in[6];
  const float* w2 = (const float*)d_in[7];
  const float* b2 = (const float*)d_in[8];
  const float* w3 = (const float*)d_in[9];
  const float* b3 = (const float*)d_in[10];
  const float* w4 = (const float*)d_in[11];
  const float* b4 = (const float*)d_in[12];

  // workspace (halves): packed weights + tail, then Z at 1MiB (16.8MB fp16)
  half_t* w0p = (half_t*)d_ws;   // 16nt*18ks*512 = 147456
  half_t* w1p = w0p + 147456;    // 65536
  half_t* w2p = w1p + 65536;
  half_t* w3p = w2p + 65536;
  half_t* w4p = w3p + 65536;     // 4096
  half_t* wtp = w4p + 4096;      // 1024
  half_t* Z = (half_t*)d_ws + 524288;  // [2*16384][256] fp16

  pack_all<<<1361, 256, 0, stream>>>(w0, w1, w2, w3, w4, w0p, w1p, w2p, w3p, w4p, wtp);
  conv_l0<<<512, 256, 0, stream>>>(feat, w0p, b0, Z);
  liif_main<<<2048, 256, 0, stream>>>(coord, cell, Z, wtp, w1p, w2p, w3p, w4p, b1, b2,
                                      b3, b4, (float*)d_out);
}

// Round 4
// 341.007 us; speedup vs baseline: 1.3120x; 1.3120x over previous
//
#include <hip/hip_runtime.h>

typedef _Float16 half_t;
typedef _Float16 half8 __attribute__((ext_vector_type(8)));
typedef float float4v __attribute__((ext_vector_type(4)));

#define MFMA16(a, b, c) __builtin_amdgcn_mfma_f32_16x16x32_f16(a, b, c, 0, 0, 0)

// ---------------------------------------------------------------------------
// One kernel packs ALL weights into MFMA B-fragment order (fp16, zero-padded)
// + w0 tail rows 576..579 to fp16 flat [4][256].
//   frag: out[((nt*nks+ks)*64+lane)*8+j] = W[ks*32+((lane>>4)<<3)+j][nt*16+(lane&15)]
// ---------------------------------------------------------------------------
__global__ void pack_all(const float* __restrict__ w0, const float* __restrict__ w1,
                         const float* __restrict__ w2, const float* __restrict__ w3,
                         const float* __restrict__ w4, half_t* __restrict__ w0p,
                         half_t* __restrict__ w1p, half_t* __restrict__ w2p,
                         half_t* __restrict__ w3p, half_t* __restrict__ w4p,
                         half_t* __restrict__ wtp) {
  const int bb = blockIdx.x;
  const float* w;
  half_t* out;
  int K, Nw, nks, base;
  if (bb < 576) {
    w = w0; out = w0p; K = 576; Nw = 256; nks = 18; base = 0;
  } else if (bb < 832) {
    w = w1; out = w1p; K = 256; Nw = 256; nks = 8; base = 576;
  } else if (bb < 1088) {
    w = w2; out = w2p; K = 256; Nw = 256; nks = 8; base = 832;
  } else if (bb < 1344) {
    w = w3; out = w3p; K = 256; Nw = 256; nks = 8; base = 1088;
  } else if (bb < 1360) {
    w = w4; out = w4p; K = 256; Nw = 3; nks = 8; base = 1344;
  } else {
    const int id = threadIdx.x;
#pragma unroll
    for (int e = 0; e < 4; e++) wtp[e * 256 + id] = (half_t)w0[576 * 256 + e * 256 + id];
    return;
  }
  const int id = (bb - base) * 256 + threadIdx.x;
  const int j = id & 7;
  const int lane = (id >> 3) & 63;
  const int t3 = id >> 9;
  const int ks = t3 % nks;
  const int nt = t3 / nks;
  const int n = nt * 16 + (lane & 15);
  const int k = ks * 32 + ((lane >> 4) << 3) + j;
  float v = (k < K && n < Nw) ? w[k * Nw + n] : 0.0f;
  out[id] = (half_t)v;
}

// ---------------------------------------------------------------------------
// Z = conv3x3(feat, W0[0:576]) + b0, position-major fp16: Z[pos][256].
// ---------------------------------------------------------------------------
__global__ __launch_bounds__(256, 2) void conv_l0(
    const float* __restrict__ feat, const half_t* __restrict__ w0p,
    const float* __restrict__ b0, half_t* __restrict__ Z) {
  __shared__ alignas(16) half_t Xc[2][64][40];
  const int tid = threadIdx.x;
  const int lane = tid & 63, wave = tid >> 6, quad = lane >> 4, l15 = lane & 15;
  const int blk = blockIdx.x;
  const int b = blk >> 8;
  const int h = (blk >> 1) & 127;
  const int wbase = (blk & 1) << 6;
  const float* featB = feat + b * (64 * 128 * 128);

  auto stage = [&](int ks, int buf) {
#pragma unroll
    for (int e = 0; e < 8; e++) {
      const int idx = e * 256 + tid;
      const int row = idx >> 5;
      const int col = idx & 31;
      const int kk = ks * 32 + col;
      const int c = kk / 9;
      const int w9 = kk - c * 9;
      const int di = w9 / 3;
      const int dj = w9 - di * 3;
      const int y = h + di - 1;
      const int x = wbase + row + dj - 1;
      float v = 0.0f;
      if ((unsigned)y < 128u && (unsigned)x < 128u) v = featB[(c << 14) + (y << 7) + x];
      Xc[buf][row][col] = (half_t)v;
    }
  };

  const float4v zero4 = {0.0f, 0.0f, 0.0f, 0.0f};
  float4v acc[4][4];
#pragma unroll
  for (int mt = 0; mt < 4; mt++)
#pragma unroll
    for (int jn = 0; jn < 4; jn++) acc[mt][jn] = zero4;

  half8 bcur[4], bnxt[4];
#pragma unroll
  for (int jn = 0; jn < 4; jn++)
    bcur[jn] = *(const half8*)(w0p + ((((wave * 4 + jn) * 18 + 0) * 64 + lane) << 3));
  stage(0, 0);
  __syncthreads();

#pragma unroll 1
  for (int ks = 0; ks < 18; ks++) {
    const int buf = ks & 1;
    if (ks + 1 < 18) {
      stage(ks + 1, buf ^ 1);
#pragma unroll
      for (int jn = 0; jn < 4; jn++)
        bnxt[jn] =
            *(const half8*)(w0p + ((((wave * 4 + jn) * 18 + ks + 1) * 64 + lane) << 3));
    }
    half8 a[4];
#pragma unroll
    for (int mt = 0; mt < 4; mt++)
      a[mt] = *(const half8*)(&Xc[buf][mt * 16 + l15][quad * 8]);
#pragma unroll
    for (int mt = 0; mt < 4; mt++)
#pragma unroll
      for (int jn = 0; jn < 4; jn++) acc[mt][jn] = MFMA16(a[mt], bcur[jn], acc[mt][jn]);
#pragma unroll
    for (int jn = 0; jn < 4; jn++) bcur[jn] = bnxt[jn];
    __syncthreads();
  }

  const int posbase = b * 16384 + h * 128 + wbase;
#pragma unroll
  for (int jn = 0; jn < 4; jn++) {
    const int colg = wave * 64 + jn * 16 + l15;
    const float bb = b0[colg];
#pragma unroll
    for (int mt = 0; mt < 4; mt++)
#pragma unroll
      for (int rr = 0; rr < 4; rr++) {
        const int row = mt * 16 + quad * 4 + rr;
        Z[(size_t)(posbase + row) * 256 + colg] = (half_t)(acc[mt][jn][rr] + bb);
      }
  }
}

// ---------------------------------------------------------------------------
// Fused LIIF main, M=128 tiles: 64 queries x 2 corners per GEMM pass.
// 256 threads, 2 blocks/CU (launch_bounds(256,2) -> 256 VGPR budget, NO spills).
// Per pass: on-demand Z gather + fp16 rank-4 + ReLU -> Hs[128][264];
// L1..L3 (M=128,N=256,K=256, acc[8][4]); L4 K-split; 2-corner ensemble.
// ---------------------------------------------------------------------------
__global__ __launch_bounds__(256, 2) void liif_main(
    const float* __restrict__ coord, const float* __restrict__ cell,
    const half_t* __restrict__ Zp, const half_t* __restrict__ wtp,
    const half_t* __restrict__ w1p, const half_t* __restrict__ w2p,
    const half_t* __restrict__ w3p, const half_t* __restrict__ w4p,
    const float* __restrict__ b1, const float* __restrict__ b2,
    const float* __restrict__ b3, const float* __restrict__ b4,
    float* __restrict__ outp) {
  __shared__ alignas(16) half_t Hs[128][264];   // 67584 B
  __shared__ float S4[4][128][4];               // 8192 B
  __shared__ int pos4[4][64];
  __shared__ half_t relxh[4][64], relyh[4][64];
  __shared__ half_t cellxh[64], cellyh[64];
  __shared__ float area4[4][64];
  __shared__ float oacc[64][4];
  __shared__ float totv[64];

  const int tid = threadIdx.x;
  const int lane = tid & 63;
  const int wave = tid >> 6;
  const int quad = lane >> 4;
  const int l15 = lane & 15;
  const int blk = blockIdx.x;
  const int batch = blk >> 10;

  // ---- geometry: t = tid>>6 (corner), row = tid&63 (query) ----
  {
    const int t = tid >> 6, row = tid & 63;
    const int gq = blk * 64 + row;
    const float cx0 = coord[gq * 2 + 0], cy0 = coord[gq * 2 + 1];
    const float vx = (t & 2) ? 1.0f : -1.0f;
    const float vy = (t & 1) ? 1.0f : -1.0f;
    const float r = 1.0f / 128.0f, lim = 1.0f - 1e-6f, eps = 1e-6f;
    float cx = fminf(fmaxf(cx0 + vx * r + eps, -lim), lim);
    float cy = fminf(fmaxf(cy0 + vy * r + eps, -lim), lim);
    int ix = (int)floorf((cx + 1.0f) * 64.0f);
    ix = min(max(ix, 0), 127);
    int iy = (int)floorf((cy + 1.0f) * 64.0f);
    iy = min(max(iy, 0), 127);
    float qx = -1.0f + (2.0f * ix + 1.0f) * (1.0f / 128.0f);
    float qy = -1.0f + (2.0f * iy + 1.0f) * (1.0f / 128.0f);
    float rxv = (cx0 - qx) * 128.0f;
    float ryv = (cy0 - qy) * 128.0f;
    pos4[t][row] = (batch << 14) + (ix << 7) + iy;
    relxh[t][row] = (half_t)rxv;
    relyh[t][row] = (half_t)ryv;
    area4[t][row] = fabsf(rxv * ryv) + 1e-9f;
    if (t == 0) {
      cellxh[row] = (half_t)(cell[gq * 2 + 0] * 128.0f);
      cellyh[row] = (half_t)(cell[gq * 2 + 1] * 128.0f);
      oacc[row][0] = 0.0f;
      oacc[row][1] = 0.0f;
      oacc[row][2] = 0.0f;
      totv[row] = 0.0f;
    }
  }
  __syncthreads();

  const float4v zero4 = {0.0f, 0.0f, 0.0f, 0.0f};
  const half8 zero8 = {0, 0, 0, 0, 0, 0, 0, 0};
  const int c8 = tid & 31;            // fixed 8-channel block
  const int rbase = (tid >> 5) * 16;  // rows rbase..rbase+15 of the 128-tile

  // per-thread rank-4 tail weights (fp16, fixed channels)
  const half8 wt0 = *(const half8*)(wtp + 0 * 256 + c8 * 8);
  const half8 wt1 = *(const half8*)(wtp + 1 * 256 + c8 * 8);
  const half8 wt2 = *(const half8*)(wtp + 2 * 256 + c8 * 8);
  const half8 wt3 = *(const half8*)(wtp + 3 * 256 + c8 * 8);

  half8 bcur[4], bnxt[4], bf4[2];
#pragma unroll
  for (int jn = 0; jn < 4; jn++)
    bcur[jn] = *(const half8*)(w1p + ((((wave * 4 + jn) * 8 + 0) * 64 + lane) << 3));

#pragma unroll 1
  for (int p = 0; p < 2; p++) {
    // ---- gather Z + rank-4 + ReLU -> Hs (rows 0..63 corner 2p, 64..127 2p+1)
#pragma unroll
    for (int e = 0; e < 16; e++) {
      const int r = rbase + e;
      const int corner = 2 * p + (r >> 6);
      const int qrow = r & 63;
      const half8 z =
          *(const half8*)(Zp + ((size_t)pos4[corner][qrow] << 8) + c8 * 8);
      const half_t rx = relxh[corner][qrow], ry = relyh[corner][qrow];
      const half_t cx = cellxh[qrow], cy = cellyh[qrow];
      const half8 rx8 = {rx, rx, rx, rx, rx, rx, rx, rx};
      const half8 ry8 = {ry, ry, ry, ry, ry, ry, ry, ry};
      const half8 cx8 = {cx, cx, cx, cx, cx, cx, cx, cx};
      const half8 cy8 = {cy, cy, cy, cy, cy, cy, cy, cy};
      half8 v = z + rx8 * wt0 + ry8 * wt1 + cx8 * wt2 + cy8 * wt3;
      v = __builtin_elementwise_max(v, zero8);
      *(half8*)(&Hs[r][c8 * 8]) = v;
    }
    __syncthreads();

    // ---- layers 1..3: M=128, N=256 (4x64 over waves), K=256 ----
    float4v acc[8][4];
#pragma unroll 1
    for (int L = 0; L < 3; L++) {
      const half_t* wp = (L == 0) ? w1p : (L == 1) ? w2p : w3p;
      const float* bp = (L == 0) ? b1 : (L == 1) ? b2 : b3;
#pragma unroll
      for (int mt = 0; mt < 8; mt++)
#pragma unroll
        for (int jn = 0; jn < 4; jn++) acc[mt][jn] = zero4;
#pragma unroll 1
      for (int ks = 0; ks < 8; ks++) {
        if (ks + 1 < 8) {
#pragma unroll
          for (int jn = 0; jn < 4; jn++)
            bnxt[jn] =
                *(const half8*)(wp + ((((wave * 4 + jn) * 8 + ks + 1) * 64 + lane) << 3));
        }
        half8 a[8];
#pragma unroll
        for (int mt = 0; mt < 8; mt++)
          a[mt] = *(const half8*)(&Hs[mt * 16 + l15][ks * 32 + quad * 8]);
#pragma unroll
        for (int mt = 0; mt < 8; mt++)
#pragma unroll
          for (int jn = 0; jn < 4; jn++)
            acc[mt][jn] = MFMA16(a[mt], bcur[jn], acc[mt][jn]);
#pragma unroll
        for (int jn = 0; jn < 4; jn++) bcur[jn] = bnxt[jn];
      }
      __syncthreads();  // all waves done READING Hs
      // preload next GEMM's first B-fragments (overlaps epilogue)
      if (L < 2) {
        const half_t* wpn = (L == 0) ? w2p : w3p;
#pragma unroll
        for (int jn = 0; jn < 4; jn++)
          bcur[jn] = *(const half8*)(wpn + ((((wave * 4 + jn) * 8 + 0) * 64 + lane) << 3));
      } else {
#pragma unroll
        for (int kx = 0; kx < 2; kx++)
          bf4[kx] = *(const half8*)(w4p + (((wave * 2 + kx) * 64 + lane) << 3));
      }
#pragma unroll
      for (int jn = 0; jn < 4; jn++) {
        const int colg = wave * 64 + jn * 16 + l15;
        const float bb = bp[colg];
#pragma unroll
        for (int mt = 0; mt < 8; mt++)
#pragma unroll
          for (int rr = 0; rr < 4; rr++) {
            float v = acc[mt][jn][rr] + bb;
            Hs[mt * 16 + quad * 4 + rr][colg] = (half_t)fmaxf(v, 0.0f);
          }
      }
      __syncthreads();
    }

    // ---- layer 4: 256 -> 3, K split across waves ----
    float4v acc4[8];
#pragma unroll
    for (int mt = 0; mt < 8; mt++) acc4[mt] = zero4;
#pragma unroll
    for (int kx = 0; kx < 2; kx++) {
      const int ks = wave * 2 + kx;
#pragma unroll
      for (int mt = 0; mt < 8; mt++) {
        half8 a = *(const half8*)(&Hs[mt * 16 + l15][ks * 32 + quad * 8]);
        acc4[mt] = MFMA16(a, bf4[kx], acc4[mt]);
      }
    }
    if (l15 < 4) {
#pragma unroll
      for (int mt = 0; mt < 8; mt++)
#pragma unroll
        for (int rr = 0; rr < 4; rr++)
          S4[wave][mt * 16 + quad * 4 + rr][l15] = acc4[mt][rr];
    }
    __syncthreads();

    // preload next pass's L1 first B-fragments (overlaps ensemble)
    if (p == 0) {
#pragma unroll
      for (int jn = 0; jn < 4; jn++)
        bcur[jn] = *(const half8*)(w1p + ((((wave * 4 + jn) * 8 + 0) * 64 + lane) << 3));
    }

    // ---- 2-corner ensemble (each thread owns one (qrow,j): no races) ----
    if (tid < 192) {
      const int qrow = tid / 3;
      const int j = tid - qrow * 3;
      const int ca = 2 * p, cb = 2 * p + 1;
      float pa = b4[j] + S4[0][qrow][j] + S4[1][qrow][j] + S4[2][qrow][j] + S4[3][qrow][j];
      float pb = b4[j] + S4[0][qrow + 64][j] + S4[1][qrow + 64][j] +
                 S4[2][qrow + 64][j] + S4[3][qrow + 64][j];
      oacc[qrow][j] += pa * area4[3 - ca][qrow] + pb * area4[3 - cb][qrow];
    } else if (tid < 256) {
      const int qrow = tid - 192;
      totv[qrow] += area4[2 * p][qrow] + area4[2 * p + 1][qrow];
    }
    __syncthreads();
  }

  if (tid < 192) {
    const int qrow = tid / 3;
    const int j = tid - qrow * 3;
    const int gq = blk * 64 + qrow;
    outp[gq * 3 + j] = oacc[qrow][j] / totv[qrow];
  }
}

// ---------------------------------------------------------------------------
extern "C" void kernel_launch(void* const* d_in, const int* in_sizes, int n_in,
                              void* d_out, int out_size, void* d_ws, size_t ws_size,
                              hipStream_t stream) {
  const float* feat = (const float*)d_in[0];
  const float* coord = (const float*)d_in[1];
  const float* cell = (const float*)d_in[2];
  const float* w0 = (const float*)d_in[3];
  const float* b0 = (const float*)d_in[4];
  const float* w1 = (const float*)d_in[5];
  const float* b1 = (const float*)d_in[6];
  const float* w2 = (const float*)d_in[7];
  const float* b2 = (const float*)d_in[8];
  const float* w3 = (const float*)d_in[9];
  const float* b3 = (const float*)d_in[10];
  const float* w4 = (const float*)d_in[11];
  const float* b4 = (const float*)d_in[12];

  half_t* w0p = (half_t*)d_ws;   // 147456
  half_t* w1p = w0p + 147456;    // 65536
  half_t* w2p = w1p + 65536;
  half_t* w3p = w2p + 65536;
  half_t* w4p = w3p + 65536;     // 4096
  half_t* wtp = w4p + 4096;      // 1024
  half_t* Z = (half_t*)d_ws + 524288;  // [2*16384][256] fp16

  pack_all<<<1361, 256, 0, stream>>>(w0, w1, w2, w3, w4, w0p, w1p, w2p, w3p, w4p, wtp);
  conv_l0<<<512, 256, 0, stream>>>(feat, w0p, b0, Z);
  liif_main<<<2048, 256, 0, stream>>>(coord, cell, Z, wtp, w1p, w2p, w3p, w4p, b1, b2,
                                      b3, b4, (float*)d_out);
}

// Round 5
// 336.710 us; speedup vs baseline: 1.3288x; 1.0128x over previous
//
#include <hip/hip_runtime.h>

typedef _Float16 half_t;
typedef _Float16 half4 __attribute__((ext_vector_type(4)));
typedef _Float16 half8 __attribute__((ext_vector_type(8)));
typedef float float4v __attribute__((ext_vector_type(4)));

#define MFMA16(a, b, c) __builtin_amdgcn_mfma_f32_16x16x32_f16(a, b, c, 0, 0, 0)

// ---------------------------------------------------------------------------
// Pack ALL weights into MFMA fragment order (fp16, zero-padded) + w0 tail
// rows 576..579 fp16 flat [4][256].
//   frag: out[((nt*nks+ks)*64+lane)*8+j] = W[ks*32+((lane>>4)<<3)+j][nt*16+(lane&15)]
// Serves as B-frag (k,n) or, in swapped-operand GEMMs, as A-frag (m=n, k).
// ---------------------------------------------------------------------------
__global__ void pack_all(const float* __restrict__ w0, const float* __restrict__ w1,
                         const float* __restrict__ w2, const float* __restrict__ w3,
                         const float* __restrict__ w4, half_t* __restrict__ w0p,
                         half_t* __restrict__ w1p, half_t* __restrict__ w2p,
                         half_t* __restrict__ w3p, half_t* __restrict__ w4p,
                         half_t* __restrict__ wtp) {
  const int bb = blockIdx.x;
  const float* w;
  half_t* out;
  int K, Nw, nks, base;
  if (bb < 576) {
    w = w0; out = w0p; K = 576; Nw = 256; nks = 18; base = 0;
  } else if (bb < 832) {
    w = w1; out = w1p; K = 256; Nw = 256; nks = 8; base = 576;
  } else if (bb < 1088) {
    w = w2; out = w2p; K = 256; Nw = 256; nks = 8; base = 832;
  } else if (bb < 1344) {
    w = w3; out = w3p; K = 256; Nw = 256; nks = 8; base = 1088;
  } else if (bb < 1360) {
    w = w4; out = w4p; K = 256; Nw = 3; nks = 8; base = 1344;
  } else {
    const int id = threadIdx.x;
#pragma unroll
    for (int e = 0; e < 4; e++) wtp[e * 256 + id] = (half_t)w0[576 * 256 + e * 256 + id];
    return;
  }
  const int id = (bb - base) * 256 + threadIdx.x;
  const int j = id & 7;
  const int lane = (id >> 3) & 63;
  const int t3 = id >> 9;
  const int ks = t3 % nks;
  const int nt = t3 / nks;
  const int n = nt * 16 + (lane & 15);
  const int k = ks * 32 + ((lane >> 4) << 3) + j;
  float v = (k < K && n < Nw) ? w[k * Nw + n] : 0.0f;
  out[id] = (half_t)v;
}

// ---------------------------------------------------------------------------
// Z = conv3x3(feat, W0[0:576]) + b0, position-major fp16: Z[pos][256].
// Swapped-operand MFMA (A=weights, B=patch acts) -> b64 Z stores.
// Staging: one wave loads one (c,di,dj) across 64 consecutive x (coalesced).
// ---------------------------------------------------------------------------
__global__ __launch_bounds__(256, 2) void conv_l0(
    const float* __restrict__ feat, const half_t* __restrict__ w0p,
    const float* __restrict__ b0, half_t* __restrict__ Z) {
  __shared__ alignas(16) half_t Xc[2][64][40];
  const int tid = threadIdx.x;
  const int lane = tid & 63, wave = tid >> 6, quad = lane >> 4, l15 = lane & 15;
  const int blk = blockIdx.x;
  const int b = blk >> 8;
  const int h = (blk >> 1) & 127;
  const int wbase = (blk & 1) << 6;
  const float* featB = feat + b * (64 * 128 * 128);

  auto stage = [&](int ks, int buf) {
#pragma unroll
    for (int e = 0; e < 2; e++) {
      const int idx = e * 256 + tid;
      const int row = idx & 63;  // position (x offset) -> lane: coalesced loads
      const int cp = idx >> 6;   // 0..7: which 4-wide k group
      half4 hv;
#pragma unroll
      for (int u = 0; u < 4; u++) {
        const int kk = ks * 32 + cp * 4 + u;
        const int c = kk / 9;
        const int w9 = kk - c * 9;
        const int di = w9 / 3;
        const int dj = w9 - di * 3;
        const int y = h + di - 1;
        const int x = wbase + row + dj - 1;
        float v = 0.0f;
        if ((unsigned)y < 128u && (unsigned)x < 128u) v = featB[(c << 14) + (y << 7) + x];
        hv[u] = (half_t)v;
      }
      *(half4*)(&Xc[buf][row][cp * 4]) = hv;
    }
  };

  const float4v zero4 = {0.0f, 0.0f, 0.0f, 0.0f};
  float4v acc[4][4];
#pragma unroll
  for (int mt = 0; mt < 4; mt++)
#pragma unroll
    for (int jn = 0; jn < 4; jn++) acc[mt][jn] = zero4;

  half8 bcur[4], bnxt[4];
#pragma unroll
  for (int jn = 0; jn < 4; jn++)
    bcur[jn] = *(const half8*)(w0p + ((((wave * 4 + jn) * 18 + 0) * 64 + lane) << 3));
  stage(0, 0);
  __syncthreads();

#pragma unroll 1
  for (int ks = 0; ks < 18; ks++) {
    const int buf = ks & 1;
    if (ks + 1 < 18) {
      stage(ks + 1, buf ^ 1);
#pragma unroll
      for (int jn = 0; jn < 4; jn++)
        bnxt[jn] =
            *(const half8*)(w0p + ((((wave * 4 + jn) * 18 + ks + 1) * 64 + lane) << 3));
    }
    half8 a[4];
#pragma unroll
    for (int mt = 0; mt < 4; mt++)
      a[mt] = *(const half8*)(&Xc[buf][mt * 16 + l15][quad * 8]);
#pragma unroll
    for (int mt = 0; mt < 4; mt++)
#pragma unroll
      for (int jn = 0; jn < 4; jn++)
        acc[mt][jn] = MFMA16(bcur[jn], a[mt], acc[mt][jn]);  // swapped: D[n][pos]
#pragma unroll
    for (int jn = 0; jn < 4; jn++) bcur[jn] = bnxt[jn];
    __syncthreads();
  }

  const int posbase = b * 16384 + h * 128 + wbase;
#pragma unroll
  for (int jn = 0; jn < 4; jn++) {
    const float4v bb4 = *(const float4v*)(b0 + wave * 64 + jn * 16 + quad * 4);
#pragma unroll
    for (int mt = 0; mt < 4; mt++) {
      half4 hv;
#pragma unroll
      for (int rr = 0; rr < 4; rr++) hv[rr] = (half_t)(acc[mt][jn][rr] + bb4[rr]);
      *(half4*)(&Z[(size_t)(posbase + mt * 16 + l15) * 256 + wave * 64 + jn * 16 +
                   quad * 4]) = hv;
    }
  }
}

// ---------------------------------------------------------------------------
// Fused LIIF main, M=128 tiles (64 queries x 2 corners), 2 blocks/CU.
// L1..L3 use swapped-operand MFMA: A=weight frag, B=activation frag (same b128
// LDS reads), D[row=n][col=q] -> epilogue is ds_write_b64 (4 consecutive
// channels per lane) instead of 4 scalar b16 column writes.
// ---------------------------------------------------------------------------
__global__ __launch_bounds__(256, 2) void liif_main(
    const float* __restrict__ coord, const float* __restrict__ cell,
    const half_t* __restrict__ Zp, const half_t* __restrict__ wtp,
    const half_t* __restrict__ w1p, const half_t* __restrict__ w2p,
    const half_t* __restrict__ w3p, const half_t* __restrict__ w4p,
    const float* __restrict__ b1, const float* __restrict__ b2,
    const float* __restrict__ b3, const float* __restrict__ b4,
    float* __restrict__ outp) {
  __shared__ alignas(16) half_t Hs[128][264];  // 67584 B
  __shared__ float S4[4][128][4];              // 8192 B
  __shared__ int pos4[4][64];
  __shared__ half_t relxh[4][64], relyh[4][64];
  __shared__ half_t cellxh[64], cellyh[64];
  __shared__ float area4[4][64];
  __shared__ float oacc[64][4];
  __shared__ float totv[64];

  const int tid = threadIdx.x;
  const int lane = tid & 63;
  const int wave = tid >> 6;
  const int quad = lane >> 4;
  const int l15 = lane & 15;
  const int blk = blockIdx.x;
  const int batch = blk >> 10;

  // ---- geometry: t = tid>>6 (corner), row = tid&63 (query) ----
  {
    const int t = tid >> 6, row = tid & 63;
    const int gq = blk * 64 + row;
    const float cx0 = coord[gq * 2 + 0], cy0 = coord[gq * 2 + 1];
    const float vx = (t & 2) ? 1.0f : -1.0f;
    const float vy = (t & 1) ? 1.0f : -1.0f;
    const float r = 1.0f / 128.0f, lim = 1.0f - 1e-6f, eps = 1e-6f;
    float cx = fminf(fmaxf(cx0 + vx * r + eps, -lim), lim);
    float cy = fminf(fmaxf(cy0 + vy * r + eps, -lim), lim);
    int ix = (int)floorf((cx + 1.0f) * 64.0f);
    ix = min(max(ix, 0), 127);
    int iy = (int)floorf((cy + 1.0f) * 64.0f);
    iy = min(max(iy, 0), 127);
    float qx = -1.0f + (2.0f * ix + 1.0f) * (1.0f / 128.0f);
    float qy = -1.0f + (2.0f * iy + 1.0f) * (1.0f / 128.0f);
    float rxv = (cx0 - qx) * 128.0f;
    float ryv = (cy0 - qy) * 128.0f;
    pos4[t][row] = (batch << 14) + (ix << 7) + iy;
    relxh[t][row] = (half_t)rxv;
    relyh[t][row] = (half_t)ryv;
    area4[t][row] = fabsf(rxv * ryv) + 1e-9f;
    if (t == 0) {
      cellxh[row] = (half_t)(cell[gq * 2 + 0] * 128.0f);
      cellyh[row] = (half_t)(cell[gq * 2 + 1] * 128.0f);
      oacc[row][0] = 0.0f;
      oacc[row][1] = 0.0f;
      oacc[row][2] = 0.0f;
      totv[row] = 0.0f;
    }
  }
  __syncthreads();

  const float4v zero4 = {0.0f, 0.0f, 0.0f, 0.0f};
  const half8 zero8 = {0, 0, 0, 0, 0, 0, 0, 0};
  const int c8 = tid & 31;            // fixed 8-channel block
  const int rbase = (tid >> 5) * 16;  // rows rbase..rbase+15 of the 128-tile

  // per-thread rank-4 tail weights (fp16, fixed channels)
  const half8 wt0 = *(const half8*)(wtp + 0 * 256 + c8 * 8);
  const half8 wt1 = *(const half8*)(wtp + 1 * 256 + c8 * 8);
  const half8 wt2 = *(const half8*)(wtp + 2 * 256 + c8 * 8);
  const half8 wt3 = *(const half8*)(wtp + 3 * 256 + c8 * 8);

  half8 bcur[4], bnxt[4], bf4[2];
#pragma unroll
  for (int jn = 0; jn < 4; jn++)
    bcur[jn] = *(const half8*)(w1p + ((((wave * 4 + jn) * 8 + 0) * 64 + lane) << 3));

#pragma unroll 1
  for (int p = 0; p < 2; p++) {
    // ---- gather Z + rank-4 + ReLU -> Hs (rows 0..63 corner 2p, 64..127 2p+1)
#pragma unroll
    for (int e = 0; e < 16; e++) {
      const int r = rbase + e;
      const int corner = 2 * p + (r >> 6);
      const int qrow = r & 63;
      const half8 z = *(const half8*)(Zp + ((size_t)pos4[corner][qrow] << 8) + c8 * 8);
      const half_t rx = relxh[corner][qrow], ry = relyh[corner][qrow];
      const half_t cx = cellxh[qrow], cy = cellyh[qrow];
      const half8 rx8 = {rx, rx, rx, rx, rx, rx, rx, rx};
      const half8 ry8 = {ry, ry, ry, ry, ry, ry, ry, ry};
      const half8 cx8 = {cx, cx, cx, cx, cx, cx, cx, cx};
      const half8 cy8 = {cy, cy, cy, cy, cy, cy, cy, cy};
      half8 v = z + rx8 * wt0 + ry8 * wt1 + cx8 * wt2 + cy8 * wt3;
      v = __builtin_elementwise_max(v, zero8);
      *(half8*)(&Hs[r][c8 * 8]) = v;
    }
    __syncthreads();

    // ---- layers 1..3: M=128, N=256 (4x64 over waves), K=256 (swapped) ----
    float4v acc[8][4];
#pragma unroll 1
    for (int L = 0; L < 3; L++) {
      const half_t* wp = (L == 0) ? w1p : (L == 1) ? w2p : w3p;
      const float* bp = (L == 0) ? b1 : (L == 1) ? b2 : b3;
#pragma unroll
      for (int mt = 0; mt < 8; mt++)
#pragma unroll
        for (int jn = 0; jn < 4; jn++) acc[mt][jn] = zero4;
#pragma unroll 1
      for (int ks = 0; ks < 8; ks++) {
        if (ks + 1 < 8) {
#pragma unroll
          for (int jn = 0; jn < 4; jn++)
            bnxt[jn] =
                *(const half8*)(wp + ((((wave * 4 + jn) * 8 + ks + 1) * 64 + lane) << 3));
        }
        half8 a[8];
#pragma unroll
        for (int mt = 0; mt < 8; mt++)
          a[mt] = *(const half8*)(&Hs[mt * 16 + l15][ks * 32 + quad * 8]);
#pragma unroll
        for (int mt = 0; mt < 8; mt++)
#pragma unroll
          for (int jn = 0; jn < 4; jn++)
            acc[mt][jn] = MFMA16(bcur[jn], a[mt], acc[mt][jn]);  // swapped
#pragma unroll
        for (int jn = 0; jn < 4; jn++) bcur[jn] = bnxt[jn];
      }
      __syncthreads();  // all waves done READING Hs
      // preload next GEMM's first fragments (overlaps epilogue)
      if (L < 2) {
        const half_t* wpn = (L == 0) ? w2p : w3p;
#pragma unroll
        for (int jn = 0; jn < 4; jn++)
          bcur[jn] = *(const half8*)(wpn + ((((wave * 4 + jn) * 8 + 0) * 64 + lane) << 3));
      } else {
#pragma unroll
        for (int kx = 0; kx < 2; kx++)
          bf4[kx] = *(const half8*)(w4p + (((wave * 2 + kx) * 64 + lane) << 3));
      }
      // epilogue: D[row=n=quad*4+rr][col=q=l15] -> one b64 write per (mt,jn)
#pragma unroll
      for (int jn = 0; jn < 4; jn++) {
        const float4v bb4 = *(const float4v*)(bp + wave * 64 + jn * 16 + quad * 4);
#pragma unroll
        for (int mt = 0; mt < 8; mt++) {
          half4 hv;
#pragma unroll
          for (int rr = 0; rr < 4; rr++)
            hv[rr] = (half_t)fmaxf(acc[mt][jn][rr] + bb4[rr], 0.0f);
          *(half4*)(&Hs[mt * 16 + l15][wave * 64 + jn * 16 + quad * 4]) = hv;
        }
      }
      __syncthreads();
    }

    // ---- layer 4: 256 -> 3, K split across waves (standard orientation) ----
    float4v acc4[8];
#pragma unroll
    for (int mt = 0; mt < 8; mt++) acc4[mt] = zero4;
#pragma unroll
    for (int kx = 0; kx < 2; kx++) {
      const int ks = wave * 2 + kx;
#pragma unroll
      for (int mt = 0; mt < 8; mt++) {
        half8 a = *(const half8*)(&Hs[mt * 16 + l15][ks * 32 + quad * 8]);
        acc4[mt] = MFMA16(a, bf4[kx], acc4[mt]);
      }
    }
    if (l15 < 4) {
#pragma unroll
      for (int mt = 0; mt < 8; mt++)
#pragma unroll
        for (int rr = 0; rr < 4; rr++)
          S4[wave][mt * 16 + quad * 4 + rr][l15] = acc4[mt][rr];
    }
    __syncthreads();

    // preload next pass's L1 first fragments (overlaps ensemble)
    if (p == 0) {
#pragma unroll
      for (int jn = 0; jn < 4; jn++)
        bcur[jn] = *(const half8*)(w1p + ((((wave * 4 + jn) * 8 + 0) * 64 + lane) << 3));
    }

    // ---- 2-corner ensemble ----
    if (tid < 192) {
      const int qrow = tid / 3;
      const int j = tid - qrow * 3;
      const int ca = 2 * p, cb = 2 * p + 1;
      float pa = b4[j] + S4[0][qrow][j] + S4[1][qrow][j] + S4[2][qrow][j] + S4[3][qrow][j];
      float pb = b4[j] + S4[0][qrow + 64][j] + S4[1][qrow + 64][j] +
                 S4[2][qrow + 64][j] + S4[3][qrow + 64][j];
      oacc[qrow][j] += pa * area4[3 - ca][qrow] + pb * area4[3 - cb][qrow];
    } else if (tid < 256) {
      const int qrow = tid - 192;
      totv[qrow] += area4[2 * p][qrow] + area4[2 * p + 1][qrow];
    }
    __syncthreads();
  }

  if (tid < 192) {
    const int qrow = tid / 3;
    const int j = tid - qrow * 3;
    const int gq = blk * 64 + qrow;
    outp[gq * 3 + j] = oacc[qrow][j] / totv[qrow];
  }
}

// ---------------------------------------------------------------------------
extern "C" void kernel_launch(void* const* d_in, const int* in_sizes, int n_in,
                              void* d_out, int out_size, void* d_ws, size_t ws_size,
                              hipStream_t stream) {
  const float* feat = (const float*)d_in[0];
  const float* coord = (const float*)d_in[1];
  const float* cell = (const float*)d_in[2];
  const float* w0 = (const float*)d_in[3];
  const float* b0 = (const float*)d_in[4];
  const float* w1 = (const float*)d_in[5];
  const float* b1 = (const float*)d_in[6];
  const float* w2 = (const float*)d_in[7];
  const float* b2 = (const float*)d_in[8];
  const float* w3 = (const float*)d_in[9];
  const float* b3 = (const float*)d_in[10];
  const float* w4 = (const float*)d_in[11];
  const float* b4 = (const float*)d_in[12];

  half_t* w0p = (half_t*)d_ws;   // 147456
  half_t* w1p = w0p + 147456;    // 65536
  half_t* w2p = w1p + 65536;
  half_t* w3p = w2p + 65536;
  half_t* w4p = w3p + 65536;     // 4096
  half_t* wtp = w4p + 4096;      // 1024
  half_t* Z = (half_t*)d_ws + 524288;  // [2*16384][256] fp16

  pack_all<<<1361, 256, 0, stream>>>(w0, w1, w2, w3, w4, w0p, w1p, w2p, w3p, w4p, wtp);
  conv_l0<<<512, 256, 0, stream>>>(feat, w0p, b0, Z);
  liif_main<<<2048, 256, 0, stream>>>(coord, cell, Z, wtp, w1p, w2p, w3p, w4p, b1, b2,
                                      b3, b4, (float*)d_out);
}